// Round 11
// baseline (9463.700 us; speedup 1.0000x reference)
//
#include <hip/hip_runtime.h>
#include <hip/hip_bf16.h>

typedef __attribute__((ext_vector_type(8))) __bf16 bf16x8;
typedef __attribute__((ext_vector_type(4))) float f32x4;
typedef __attribute__((ext_vector_type(4))) unsigned uint4v;

static constexpr int BB = 64;    // batch
static constexpr int SS = 512;   // seq len
static constexpr int IN = 512;   // input dim
static constexpr int HH = 1024;  // hidden
static constexpr int OO = 512;   // output dim
static constexpr int KK = 1536;  // H + I (combined recurrent K)
static constexpr int G4 = 4096;  // 4*H
static constexpr int NBLK = 256; // recurrent blocks (1 per CU)
static constexpr int COLS = 16;  // gate-cols per recurrent block (G4/NBLK)
static constexpr int HCPB = 4;   // h-cols per recurrent block (HH/NBLK)
static constexpr unsigned SENT = 0x7FC07FC0u;  // 2x bf16 NaN: unreachable for |h|<1

__device__ __forceinline__ f32x4 mfma16(bf16x8 a, bf16x8 b, f32x4 c) {
  return __builtin_amdgcn_mfma_f32_16x16x32_bf16(a, b, c, 0, 0, 0);
}
__device__ __forceinline__ float sigm(float x) { return 1.f / (1.f + __expf(-x)); }
__device__ __forceinline__ float tanh_f(float x) { return 1.f - 2.f / (1.f + __expf(2.f * x)); }

// Gate-col permutation: p = n*16 + g*4 + r  <->  gate g, hcol = n*4 + r.

__global__ void k_convw(const float* Wf, const float* Wi, const float* Wo, const float* Wc,
                        const float* bfv, const float* biv, const float* bov, const float* bcv,
                        __bf16* Wcomb, float* biasp) {
  int p = blockIdx.x;                       // 0..4095
  int g = (p >> 2) & 3;
  int hcol = ((p >> 4) << 2) | (p & 3);
  const float* Wg = (g == 0) ? Wf : (g == 1) ? Wi : (g == 2) ? Wo : Wc;
  const float* bg = (g == 0) ? bfv : (g == 1) ? biv : (g == 2) ? bov : bcv;
  const float* src = Wg + (size_t)hcol * KK;
  for (int k = threadIdx.x; k < KK; k += 256) Wcomb[(size_t)p * KK + k] = (__bf16)src[k];
  if (threadIdx.x == 0) biasp[p] = bg[hcol];
}

// xb[(t*64+b)*512 + k] = bf16(x[b][t][k])
__global__ void k_convx(const float* x, __bf16* xb) {
  size_t idx = (size_t)blockIdx.x * 256 + threadIdx.x;  // 16,777,216
  int k = idx & 511;
  size_t row = idx >> 9;
  int t = (int)(row >> 6), b = (int)(row & 63);
  xb[idx] = (__bf16)x[((size_t)b * SS + t) * IN + k];
}

__global__ void k_convfc(const float* Wfc, __bf16* Wfcb) {
  size_t i = (size_t)blockIdx.x * 256 + threadIdx.x;  // 524,288
  Wfcb[i] = (__bf16)Wfc[i];
}

// Pre-poison h slabs: slab 0 (h_{-1}) = 0.0, slabs 1..512 = NaN sentinel.
__global__ void k_fillh(unsigned* hsb32) {
  size_t i = (size_t)blockIdx.x * 256 + threadIdx.x;  // 16,809,984 u32
  hsb32[i] = (i < (size_t)(BB * HH / 2)) ? 0u : SENT;
}

__global__ void k_diag(float* out, float v) { out[0] = v; }

__device__ __forceinline__ unsigned long long ald64(const unsigned long long* p) {
  return __hip_atomic_load(p, __ATOMIC_RELAXED, __HIP_MEMORY_SCOPE_AGENT);
}
__device__ __forceinline__ bool stale4(uint4v u) {
  return (u[0] == SENT) | (u[1] == SENT) | (u[2] == SENT) | (u[3] == SENT);
}

// Persistent recurrent kernel: 256 blocks x 256 thr. Sentinel-in-data protocol with
// HALF-BATCHED validated loads (register-bounded): 16 fragments eagerly issued as
// plain 16B loads (cached OK: write-once slabs make stale reads detectable, never
// wrong), validated in registers, stragglers re-polled via agent-scope u64 atomics
// batched per round (~1 LLC RT/round). Two halves pipelined against x-part and
// h-MFMAs. No fences, flags, drains, or in-loop barriers; waves free-run.
__global__ __launch_bounds__(256) void k_lstm(const __bf16* __restrict__ Wcomb,
                                              const __bf16* __restrict__ xb,
                                              const float* __restrict__ biasp,
                                              __bf16* __restrict__ hsb,
                                              float* __restrict__ tail) {
  const int n = blockIdx.x;
  const int tid = threadIdx.x;
  const int w = tid >> 6, l = tid & 63;
  const int l16 = l & 15, lk = l >> 4;
  __shared__ __bf16 wl[48 * 512];   // 48 chunks x (4 lk x 16 cols x 8) bf16 = 49,152 B
  __shared__ float gt[64][20];      // MFMA D spill (wave-local rows; 2-way bank = free)
  for (int i = tid; i < COLS * (KK / 8); i += 256) {  // 16*192 = 3072
    int c = i / 192, kch = i % 192;
    bf16x8 v = *(const bf16x8*)(Wcomb + ((size_t)(n * COLS + c)) * KK + kch * 8);
    int chunk = kch >> 2, lkw = kch & 3;
    *(bf16x8*)(wl + ((chunk * 64 + lkw * 16 + c) << 3)) = v;
  }
  const int br = tid >> 2, rr = tid & 3;  // act mapping: row br (= wave-local), col-off rr
  const float bias_f = biasp[n * COLS + 0 + rr];
  const float bias_i = biasp[n * COLS + 4 + rr];
  const float bias_o = biasp[n * COLS + 8 + rr];
  const float bias_c = biasp[n * COLS + 12 + rr];
  __syncthreads();  // weights staged (the only block barrier in the kernel)
  const size_t aoffH = (size_t)(w * 16 + l16) * HH + lk * 8;
  const size_t aoffX = (size_t)(w * 16 + l16) * IN + lk * 8;
  const __bf16* wlane = wl + ((lk * 16 + l16) << 3);
  const f32x4 vz = {0.f, 0.f, 0.f, 0.f};
  float cst = 0.f;
  for (int t = 0; t < SS; ++t) {
    const __bf16* hp = hsb + (size_t)t * (BB * HH);
    const __bf16* xp = xb + (size_t)t * (BB * IN);
    const uint4v* h16 = (const uint4v*)(hp + aoffH);           // frag c at index 4c
    const unsigned long long* hq = (const unsigned long long*)(hp + aoffH);
    // ---- phase 1: eager-issue half A (chunks 0..15; plain cached loads) ----
    uint4v hf[16];
#pragma unroll
    for (int c = 0; c < 16; ++c) hf[c] = h16[4 * c];
    // ---- phase 2: x-part MFMAs (cover half-A load latency) ----
    f32x4 a0 = vz, a1 = vz;
#pragma unroll
    for (int kc = 0; kc < IN; kc += 64) {   // chunks 32..47
      bf16x8 av0 = *(const bf16x8*)(xp + aoffX + kc);
      bf16x8 av1 = *(const bf16x8*)(xp + aoffX + kc + 32);
      bf16x8 bv0 = *(const bf16x8*)(wlane + (32 + kc / 32) * 512);
      bf16x8 bv1 = *(const bf16x8*)(wlane + (33 + kc / 32) * 512);
      a0 = mfma16(av0, bv0, a0);
      a1 = mfma16(av1, bv1, a1);
    }
    // ---- phase 3: validate half A; batched atomic re-poll for stragglers ----
    unsigned st = 0;
#pragma unroll
    for (int c = 0; c < 16; ++c) st |= (unsigned)stale4(hf[c]) << c;
    while (__builtin_expect(__any((int)(st != 0u)), 0)) {
      unsigned ns = 0;
#pragma unroll
      for (int c = 0; c < 16; ++c) {
        if (st & (1u << c)) {
          unsigned long long a = ald64(hq + 8 * c);
          unsigned long long b = ald64(hq + 8 * c + 1);
          hf[c][0] = (unsigned)a; hf[c][1] = (unsigned)(a >> 32);
          hf[c][2] = (unsigned)b; hf[c][3] = (unsigned)(b >> 32);
          ns |= (unsigned)stale4(hf[c]) << c;
        }
      }
      st = ns;
    }
    // ---- phase 4: eager-issue half B (chunks 16..31), then MFMA half A ----
    uint4v hg[16];
#pragma unroll
    for (int c = 0; c < 16; ++c) hg[c] = h16[4 * (16 + c)];
#pragma unroll
    for (int c = 0; c < 16; ++c) {
      bf16x8 av = __builtin_bit_cast(bf16x8, hf[c]);
      bf16x8 bv = *(const bf16x8*)(wlane + c * 512);
      if (c & 1) a1 = mfma16(av, bv, a1);
      else       a0 = mfma16(av, bv, a0);
    }
    // ---- phase 5: validate half B; re-poll; MFMA half B ----
    st = 0;
#pragma unroll
    for (int c = 0; c < 16; ++c) st |= (unsigned)stale4(hg[c]) << c;
    while (__builtin_expect(__any((int)(st != 0u)), 0)) {
      unsigned ns = 0;
#pragma unroll
      for (int c = 0; c < 16; ++c) {
        if (st & (1u << c)) {
          unsigned long long a = ald64(hq + 8 * (16 + c));
          unsigned long long b = ald64(hq + 8 * (16 + c) + 1);
          hg[c][0] = (unsigned)a; hg[c][1] = (unsigned)(a >> 32);
          hg[c][2] = (unsigned)b; hg[c][3] = (unsigned)(b >> 32);
          ns |= (unsigned)stale4(hg[c]) << c;
        }
      }
      st = ns;
    }
#pragma unroll
    for (int c = 0; c < 16; ++c) {
      bf16x8 av = __builtin_bit_cast(bf16x8, hg[c]);
      bf16x8 bv = *(const bf16x8*)(wlane + (16 + c) * 512);
      if (c & 1) a1 = mfma16(av, bv, a1);
      else       a0 = mfma16(av, bv, a0);
    }
    f32x4 s = a0 + a1;
#pragma unroll
    for (int q = 0; q < 4; ++q) gt[w * 16 + lk * 4 + q][l16] = s[q];  // D: row=lk*4+q, col=l16
    // gt exchange is wave-local (wave w writes rows [16w,16w+16), act reads row br in range)
    asm volatile("s_waitcnt lgkmcnt(0)" ::: "memory");
    // ---- activations + h/c update (1 gate-set per thread) ----
    float f_ = gt[br][rr] + bias_f;
    float i_ = gt[br][4 + rr] + bias_i;
    float o_ = gt[br][8 + rr] + bias_o;
    float g_ = gt[br][12 + rr] + bias_c;
    cst = sigm(f_) * cst + sigm(i_) * tanh_f(g_);
    float hv = sigm(o_) * tanh_f(cst);
    const int hcol = n * HCPB + rr;
    // publish h: packed u32 agent-scope WT store. Data arrival IS the signal.
    unsigned hb = (unsigned)__builtin_bit_cast(unsigned short, (__bf16)hv);
    unsigned nb = __shfl_down(hb, 1);
    if ((rr & 1) == 0) {
      unsigned pk = hb | (nb << 16);
      unsigned* dst = (unsigned*)(hsb + (size_t)(t + 1) * (BB * HH) + (size_t)br * HH + hcol);
      __hip_atomic_store(dst, pk, __ATOMIC_RELAXED, __HIP_MEMORY_SCOPE_AGENT);
    }
    if (t == SS - 1) {
      tail[(size_t)br * HH + hcol] = hv;
      tail[(size_t)BB * HH + (size_t)br * HH + hcol] = cst;
    }
    // no drain, no flag, no barrier: next iteration starts immediately
  }
}

// GEMM-2: out[r=b*S+t][col] = hs[t+1][b][:] . Wfc[col][:] + bfc[col]  (M=32768,N=512,K=1024)
__global__ __launch_bounds__(256) void k_gemm_out(const __bf16* __restrict__ hsb,
                                                  const __bf16* __restrict__ Wfcb,
                                                  const float* __restrict__ bfc,
                                                  float* __restrict__ out) {
  int w = threadIdx.x >> 6, l = threadIdx.x & 63;
  int l16 = l & 15, lk = l >> 4;
  int Mbase = blockIdx.x * 64, Nbase = blockIdx.y * 64;
  int rA = Mbase + w * 16 + l16;
  int bb = rA >> 9, tt = rA & 511;
  const __bf16* Ap = hsb + ((size_t)(tt + 1) * BB + bb) * HH + lk * 8;
  const __bf16* Bp[4];
#pragma unroll
  for (int jt = 0; jt < 4; ++jt)
    Bp[jt] = Wfcb + ((size_t)(Nbase + jt * 16 + l16)) * HH + lk * 8;
  const f32x4 vz = {0.f, 0.f, 0.f, 0.f};
  f32x4 acc[4] = {vz, vz, vz, vz};
  for (int kc = 0; kc < HH; kc += 32) {
    bf16x8 a = *(const bf16x8*)(Ap + kc);
#pragma unroll
    for (int jt = 0; jt < 4; ++jt) {
      bf16x8 bv = *(const bf16x8*)(Bp[jt] + kc);
      acc[jt] = mfma16(a, bv, acc[jt]);
    }
  }
#pragma unroll
  for (int jt = 0; jt < 4; ++jt) {
    int col = Nbase + jt * 16 + l16;
    float badd = bfc[col];
#pragma unroll
    for (int q = 0; q < 4; ++q) {
      int rD = Mbase + w * 16 + lk * 4 + q;
      out[(size_t)rD * OO + col] = acc[jt][q] + badd;
    }
  }
}

extern "C" void kernel_launch(void* const* d_in, const int* in_sizes, int n_in,
                              void* d_out, int out_size, void* d_ws, size_t ws_size,
                              hipStream_t stream) {
  const float* x = (const float*)d_in[0];
  const float* Wf = (const float*)d_in[1];
  const float* Wi = (const float*)d_in[2];
  const float* Wo = (const float*)d_in[3];
  const float* Wc = (const float*)d_in[4];
  const float* bfv = (const float*)d_in[5];
  const float* biv = (const float*)d_in[6];
  const float* bov = (const float*)d_in[7];
  const float* bcv = (const float*)d_in[8];
  const float* Wfc = (const float*)d_in[9];
  const float* bfc = (const float*)d_in[10];
  float* out = (float*)d_out;

  char* ws = (char*)d_ws;
  size_t off = 0;
  auto take = [&](size_t bytes) -> char* {
    off = (off + 255) & ~(size_t)255;
    char* p = ws + off;
    off += bytes;
    return p;
  };
  __bf16* Wcomb = (__bf16*)take((size_t)G4 * KK * 2);            // 12 MB
  __bf16* Wfcb = (__bf16*)take((size_t)OO * HH * 2);             // 1 MB
  float* biasp = (float*)take((size_t)G4 * 4);                   // 16 KB
  __bf16* xb = (__bf16*)take((size_t)BB * SS * IN * 2);          // 32 MB
  __bf16* hsb = (__bf16*)take((size_t)(SS + 1) * BB * HH * 2);   // 64.1 MB
  if (off > ws_size) {
    hipLaunchKernelGGL(k_diag, dim3(1), dim3(1), 0, stream, out,
                       1.0e6f + (float)(ws_size >> 20));
    return;
  }

  hipLaunchKernelGGL(k_convw, dim3(G4), dim3(256), 0, stream,
                     Wf, Wi, Wo, Wc, bfv, biv, bov, bcv, Wcomb, biasp);
  hipLaunchKernelGGL(k_convx, dim3((BB * SS * IN) / 256), dim3(256), 0, stream, x, xb);
  hipLaunchKernelGGL(k_convfc, dim3((OO * HH) / 256), dim3(256), 0, stream, Wfc, Wfcb);
  hipLaunchKernelGGL(k_fillh, dim3(((SS + 1) * BB * HH / 2) / 256), dim3(256), 0, stream,
                     (unsigned*)hsb);

  float* tail = out + (size_t)BB * SS * OO;
  void* args[] = {(void*)&Wcomb, (void*)&xb, (void*)&biasp, (void*)&hsb, (void*)&tail};
  hipError_t cerr = hipLaunchCooperativeKernel((const void*)k_lstm, dim3(NBLK), dim3(256),
                                               args, 0, stream);
  if (cerr != hipSuccess) {
    // Diagnostic: absmax error reads ~ (1e5 + hip error code), bf16-exact for code<2048.
    hipLaunchKernelGGL(k_diag, dim3(1), dim3(1), 0, stream, out,
                       1.0e5f + (float)(int)cerr);
    return;
  }

  hipLaunchKernelGGL(k_gemm_out, dim3((BB * SS) / 64, OO / 64), dim3(256), 0, stream,
                     hsb, Wfcb, bfc, out);
}

// Round 12
// 3846.022 us; speedup vs baseline: 2.4606x; 2.4606x over previous
//
#include <hip/hip_runtime.h>
#include <hip/hip_bf16.h>

typedef __attribute__((ext_vector_type(8))) __bf16 bf16x8;
typedef __attribute__((ext_vector_type(4))) float f32x4;

static constexpr int BB = 64;    // batch
static constexpr int SS = 512;   // seq len
static constexpr int IN = 512;   // input dim
static constexpr int HH = 1024;  // hidden
static constexpr int OO = 512;   // output dim
static constexpr int KK = 1536;  // H + I (combined recurrent K)
static constexpr int G4 = 4096;  // 4*H
static constexpr int NBLK = 256; // recurrent blocks (1 per CU)
static constexpr int COLS = 16;  // gate-cols per recurrent block (G4/NBLK)
static constexpr int HCPB = 4;   // h-cols per recurrent block (HH/NBLK)

__device__ __forceinline__ f32x4 mfma16(bf16x8 a, bf16x8 b, f32x4 c) {
  return __builtin_amdgcn_mfma_f32_16x16x32_bf16(a, b, c, 0, 0, 0);
}
__device__ __forceinline__ float sigm(float x) { return 1.f / (1.f + __expf(-x)); }
__device__ __forceinline__ float tanh_f(float x) { return 1.f - 2.f / (1.f + __expf(2.f * x)); }

// Gate-col permutation: p = n*16 + g*4 + r  <->  gate g, hcol = n*4 + r.

__global__ void k_convw(const float* Wf, const float* Wi, const float* Wo, const float* Wc,
                        const float* bfv, const float* biv, const float* bov, const float* bcv,
                        __bf16* Wcomb, float* biasp) {
  int p = blockIdx.x;                       // 0..4095
  int g = (p >> 2) & 3;
  int hcol = ((p >> 4) << 2) | (p & 3);
  const float* Wg = (g == 0) ? Wf : (g == 1) ? Wi : (g == 2) ? Wo : Wc;
  const float* bg = (g == 0) ? bfv : (g == 1) ? biv : (g == 2) ? bov : bcv;
  const float* src = Wg + (size_t)hcol * KK;
  for (int k = threadIdx.x; k < KK; k += 256) Wcomb[(size_t)p * KK + k] = (__bf16)src[k];
  if (threadIdx.x == 0) biasp[p] = bg[hcol];
}

// xb[(t*64+b)*512 + k] = bf16(x[b][t][k])   (t-major rows for the recurrent A-fragments)
__global__ void k_convx(const float* x, __bf16* xb) {
  size_t idx = (size_t)blockIdx.x * 256 + threadIdx.x;  // 16,777,216
  int k = idx & 511;
  size_t row = idx >> 9;
  int t = (int)(row >> 6), b = (int)(row & 63);
  xb[idx] = (__bf16)x[((size_t)b * SS + t) * IN + k];
}

__global__ void k_convfc(const float* Wfc, __bf16* Wfcb) {
  size_t i = (size_t)blockIdx.x * 256 + threadIdx.x;  // 524,288
  Wfcb[i] = (__bf16)Wfc[i];
}

__global__ void k_zeroh0(__bf16* hsb) {
  size_t i = (size_t)blockIdx.x * 256 + threadIdx.x;  // 65,536 (slot 0 = h_{-1} = 0)
  hsb[i] = (__bf16)0.f;
}

__global__ void k_diag(float* out, float v) { out[0] = v; }

// Persistent recurrent kernel: 256 blocks x 256 thr (r8 structure; publishes via
// atomic EXCHANGE instead of WT stores). Rationale: RMWs execute at the device
// coherence point and leave the line resident there, so consumers' flag-gated
// plain loads (L2-shared per XCD) refill at LLC latency instead of bouncing to
// HBM (r8 counters: FETCH 400MB = every h-fill missing to memory; WRITE 267MB =
// 4x sector amplification of 67MB stored).
__global__ __launch_bounds__(256) void k_lstm(const __bf16* __restrict__ Wcomb,
                                              const __bf16* __restrict__ xb,
                                              const float* __restrict__ biasp,
                                              __bf16* __restrict__ hsb,
                                              float* __restrict__ tail,
                                              unsigned* __restrict__ flags) {
  const int n = blockIdx.x;
  const int tid = threadIdx.x;
  const int w = tid >> 6, l = tid & 63;
  const int l16 = l & 15, lk = l >> 4;
  __shared__ __bf16 wl[48 * 512];   // 48 chunks x (4 lk x 16 cols x 8) bf16 = 49,152 B
  __shared__ float gt[64][20];      // MFMA D spill (stride 20: worst 2-way conflict = free)
  // --- preload weight slice into LDS, fragment-major ---
  for (int i = tid; i < COLS * (KK / 8); i += 256) {  // 16*192 = 3072
    int c = i / 192, kch = i % 192;
    bf16x8 v = *(const bf16x8*)(Wcomb + ((size_t)(n * COLS + c)) * KK + kch * 8);
    int chunk = kch >> 2, lkw = kch & 3;
    *(bf16x8*)(wl + ((chunk * 64 + lkw * 16 + c) << 3)) = v;
  }
  const int br = tid >> 2, rr = tid & 3;  // this thread's (batch, hcol-offset) element
  const float bias_f = biasp[n * COLS + 0 + rr];
  const float bias_i = biasp[n * COLS + 4 + rr];
  const float bias_o = biasp[n * COLS + 8 + rr];
  const float bias_c = biasp[n * COLS + 12 + rr];
  __syncthreads();
  const size_t aoffH = (size_t)(w * 16 + l16) * HH + lk * 8;
  const size_t aoffX = (size_t)(w * 16 + l16) * IN + lk * 8;
  const __bf16* wlane = wl + ((lk * 16 + l16) << 3);
  const int startC = (n >> 3) & 15;   // stagger key: co-XCD siblings differ
  const f32x4 vz = {0.f, 0.f, 0.f, 0.f};
  float cst = 0.f;
  for (int t = 0; t < SS; ++t) {
    const __bf16* hp = hsb + (size_t)t * (BB * HH);
    const __bf16* xp = xb + (size_t)t * (BB * IN);
    f32x4 a0 = vz, a1 = vz;
    // ---- phase A: x-part (no h dependency; overlaps other blocks' step-t tail) ----
#pragma unroll
    for (int kc = 0; kc < IN; kc += 64) {   // x-part: chunks 32..47
      bf16x8 av0 = *(const bf16x8*)(xp + aoffX + kc);
      bf16x8 av1 = *(const bf16x8*)(xp + aoffX + kc + 32);
      bf16x8 bv0 = *(const bf16x8*)(wlane + (32 + kc / 32) * 512);
      bf16x8 bv1 = *(const bf16x8*)(wlane + (33 + kc / 32) * 512);
      a0 = mfma16(av0, bv0, a0);
      a1 = mfma16(av1, bv1, a1);
    }
    // ---- phase B: wait until all 256 blocks have published h_t ----
    if (tid < 64) {
      const unsigned tgt = (unsigned)t;
      for (;;) {
        unsigned f0 = __hip_atomic_load(&flags[tid * 4 + 0], __ATOMIC_RELAXED, __HIP_MEMORY_SCOPE_AGENT);
        unsigned f1 = __hip_atomic_load(&flags[tid * 4 + 1], __ATOMIC_RELAXED, __HIP_MEMORY_SCOPE_AGENT);
        unsigned f2 = __hip_atomic_load(&flags[tid * 4 + 2], __ATOMIC_RELAXED, __HIP_MEMORY_SCOPE_AGENT);
        unsigned f3 = __hip_atomic_load(&flags[tid * 4 + 3], __ATOMIC_RELAXED, __HIP_MEMORY_SCOPE_AGENT);
        bool ok = (f0 >= tgt) & (f1 >= tgt) & (f2 >= tgt) & (f3 >= tgt);
        if (__all((int)ok)) break;
        __builtin_amdgcn_s_sleep(1);
      }
    }
    __syncthreads();
    asm volatile("" ::: "memory");  // no speculative h-load hoisting above the wait
    // ---- phase C: h-part (plain cached loads: clean lines, L2-shared within XCD) ----
#pragma unroll
    for (int i = 0; i < 16; ++i) {
      int cc = (startC + i) & 15;       // 16 double-chunks of 64 k each
      int kc = cc * 64;
      bf16x8 av0 = *(const bf16x8*)(hp + aoffH + kc);
      bf16x8 av1 = *(const bf16x8*)(hp + aoffH + kc + 32);
      bf16x8 bv0 = *(const bf16x8*)(wlane + (cc * 2) * 512);
      bf16x8 bv1 = *(const bf16x8*)(wlane + (cc * 2 + 1) * 512);
      a0 = mfma16(av0, bv0, a0);
      a1 = mfma16(av1, bv1, a1);
    }
    f32x4 s = a0 + a1;
#pragma unroll
    for (int q = 0; q < 4; ++q) gt[w * 16 + lk * 4 + q][l16] = s[q];  // D: row=lk*4+q, col=l16
    // gt exchange is wave-local: wave w writes rows [16w,16w+16) and act reads exactly those.
    asm volatile("s_waitcnt lgkmcnt(0)" ::: "memory");
    // ---- phase D: activations + h/c update (parallel: 1 gate-set per thread) ----
    float f_ = gt[br][rr] + bias_f;
    float i_ = gt[br][4 + rr] + bias_i;
    float o_ = gt[br][8 + rr] + bias_o;
    float g_ = gt[br][12 + rr] + bias_c;
    cst = sigm(f_) * cst + sigm(i_) * tanh_f(g_);
    float hv = sigm(o_) * tanh_f(cst);
    const int hcol = n * HCPB + rr;
    // publish h: packed u32 via atomic EXCHANGE -> executes at coherence point,
    // line stays LLC-resident for consumers' refills.
    unsigned hb = (unsigned)__builtin_bit_cast(unsigned short, (__bf16)hv);
    unsigned nb = __shfl_down(hb, 1);
    if ((rr & 1) == 0) {
      unsigned pk = hb | (nb << 16);
      unsigned* dst = (unsigned*)(hsb + (size_t)(t + 1) * (BB * HH) + (size_t)br * HH + hcol);
      (void)__hip_atomic_exchange(dst, pk, __ATOMIC_RELAXED, __HIP_MEMORY_SCOPE_AGENT);
    }
    if (t == SS - 1) {
      tail[(size_t)br * HH + hcol] = hv;
      tail[(size_t)BB * HH + (size_t)br * HH + hcol] = cst;
    }
    // ---- phase E: arrive. Per-wave drain (RMW acks), one barrier, then flag. ----
    asm volatile("s_waitcnt vmcnt(0)" ::: "memory");
    __syncthreads();   // the only per-step block barrier
    if (t + 1 < SS && tid == 0)
      (void)__hip_atomic_exchange(&flags[n], (unsigned)(t + 1), __ATOMIC_RELAXED,
                                  __HIP_MEMORY_SCOPE_AGENT);
  }
}

// GEMM-2: out[r=b*S+t][col] = hs[t+1][b][:] . Wfc[col][:] + bfc[col]  (M=32768,N=512,K=1024)
__global__ __launch_bounds__(256) void k_gemm_out(const __bf16* __restrict__ hsb,
                                                  const __bf16* __restrict__ Wfcb,
                                                  const float* __restrict__ bfc,
                                                  float* __restrict__ out) {
  int w = threadIdx.x >> 6, l = threadIdx.x & 63;
  int l16 = l & 15, lk = l >> 4;
  int Mbase = blockIdx.x * 64, Nbase = blockIdx.y * 64;
  int rA = Mbase + w * 16 + l16;
  int bb = rA >> 9, tt = rA & 511;
  const __bf16* Ap = hsb + ((size_t)(tt + 1) * BB + bb) * HH + lk * 8;
  const __bf16* Bp[4];
#pragma unroll
  for (int jt = 0; jt < 4; ++jt)
    Bp[jt] = Wfcb + ((size_t)(Nbase + jt * 16 + l16)) * HH + lk * 8;
  const f32x4 vz = {0.f, 0.f, 0.f, 0.f};
  f32x4 acc[4] = {vz, vz, vz, vz};
  for (int kc = 0; kc < HH; kc += 32) {
    bf16x8 a = *(const bf16x8*)(Ap + kc);
#pragma unroll
    for (int jt = 0; jt < 4; ++jt) {
      bf16x8 bv = *(const bf16x8*)(Bp[jt] + kc);
      acc[jt] = mfma16(a, bv, acc[jt]);
    }
  }
#pragma unroll
  for (int jt = 0; jt < 4; ++jt) {
    int col = Nbase + jt * 16 + l16;
    float badd = bfc[col];
#pragma unroll
    for (int q = 0; q < 4; ++q) {
      int rD = Mbase + w * 16 + lk * 4 + q;
      out[(size_t)rD * OO + col] = acc[jt][q] + badd;
    }
  }
}

extern "C" void kernel_launch(void* const* d_in, const int* in_sizes, int n_in,
                              void* d_out, int out_size, void* d_ws, size_t ws_size,
                              hipStream_t stream) {
  const float* x = (const float*)d_in[0];
  const float* Wf = (const float*)d_in[1];
  const float* Wi = (const float*)d_in[2];
  const float* Wo = (const float*)d_in[3];
  const float* Wc = (const float*)d_in[4];
  const float* bfv = (const float*)d_in[5];
  const float* biv = (const float*)d_in[6];
  const float* bov = (const float*)d_in[7];
  const float* bcv = (const float*)d_in[8];
  const float* Wfc = (const float*)d_in[9];
  const float* bfc = (const float*)d_in[10];
  float* out = (float*)d_out;

  char* ws = (char*)d_ws;
  size_t off = 0;
  auto take = [&](size_t bytes) -> char* {
    off = (off + 255) & ~(size_t)255;
    char* p = ws + off;
    off += bytes;
    return p;
  };
  __bf16* Wcomb = (__bf16*)take((size_t)G4 * KK * 2);            // 12 MB
  __bf16* Wfcb = (__bf16*)take((size_t)OO * HH * 2);             // 1 MB
  float* biasp = (float*)take((size_t)G4 * 4);                   // 16 KB
  unsigned* flags = (unsigned*)take(NBLK * 4);                   // per-block flags (1 KB)
  __bf16* xb = (__bf16*)take((size_t)BB * SS * IN * 2);          // 32 MB
  __bf16* hsb = (__bf16*)take((size_t)(SS + 1) * BB * HH * 2);   // 64.1 MB
  if (off > ws_size) {
    hipLaunchKernelGGL(k_diag, dim3(1), dim3(1), 0, stream, out,
                       1.0e6f + (float)(ws_size >> 20));
    return;
  }

  hipMemsetAsync(flags, 0, NBLK * 4, stream);  // reset flags each launch (graph-replay-safe)
  hipLaunchKernelGGL(k_convw, dim3(G4), dim3(256), 0, stream,
                     Wf, Wi, Wo, Wc, bfv, biv, bov, bcv, Wcomb, biasp);
  hipLaunchKernelGGL(k_convx, dim3((BB * SS * IN) / 256), dim3(256), 0, stream, x, xb);
  hipLaunchKernelGGL(k_convfc, dim3((OO * HH) / 256), dim3(256), 0, stream, Wfc, Wfcb);
  hipLaunchKernelGGL(k_zeroh0, dim3((BB * HH) / 256), dim3(256), 0, stream, hsb);

  float* tail = out + (size_t)BB * SS * OO;
  void* args[] = {(void*)&Wcomb, (void*)&xb, (void*)&biasp, (void*)&hsb,
                  (void*)&tail, (void*)&flags};
  hipError_t cerr = hipLaunchCooperativeKernel((const void*)k_lstm, dim3(NBLK), dim3(256),
                                               args, 0, stream);
  if (cerr != hipSuccess) {
    hipLaunchKernelGGL(k_diag, dim3(1), dim3(1), 0, stream, out,
                       1.0e5f + (float)(int)cerr);
    return;
  }

  hipLaunchKernelGGL(k_gemm_out, dim3((BB * SS) / 64, OO / 64), dim3(256), 0, stream,
                     hsb, Wfcb, bfc, out);
}